// Round 1
// baseline (650.401 us; speedup 1.0000x reference)
//
#include <hip/hip_runtime.h>
#include <hip/hip_bf16.h>
#include <math.h>

typedef __bf16 bf16_t;
typedef bf16_t bf16x8 __attribute__((ext_vector_type(8)));
typedef float f32x4 __attribute__((ext_vector_type(4)));

#define T_TOK 8192
#define HDIM  1024
#define IDIM  512
#define NEXP  8
#define NTOT  12

// ---------------- async global->LDS, 16B per lane ----------------
__device__ __forceinline__ void gll16(const bf16_t* g, bf16_t* l) {
  __builtin_amdgcn_global_load_lds((__attribute__((address_space(1))) void*)g,
                                   (__attribute__((address_space(3))) void*)l,
                                   16, 0, 0);
}

// ---------------- fp32 -> bf16 cast, 8 elems/thread ----------------
__global__ void cast_bf16_kernel(const float* __restrict__ in, bf16_t* __restrict__ out,
                                 size_t n8 /* n/8 */) {
  size_t gid = (size_t)blockIdx.x * blockDim.x + threadIdx.x;
  if (gid >= n8) return;
  size_t i = gid * 8;
  float4 a = *(const float4*)&in[i];
  float4 b = *(const float4*)&in[i + 4];
  bf16x8 o;
  o[0] = (bf16_t)a.x; o[1] = (bf16_t)a.y; o[2] = (bf16_t)a.z; o[3] = (bf16_t)a.w;
  o[4] = (bf16_t)b.x; o[5] = (bf16_t)b.y; o[6] = (bf16_t)b.z; o[7] = (bf16_t)b.w;
  *(bf16x8*)&out[i] = o;
}

// ---------------- router: one wave per token ----------------
__global__ void router_kernel(const float* __restrict__ x, const float* __restrict__ rw,
                              const float* __restrict__ bias,
                              float* __restrict__ combine, float* __restrict__ zscale) {
  int t = blockIdx.x;
  int l = threadIdx.x;  // 64 lanes
  const float4* xr = (const float4*)(x + (size_t)t * HDIM);
  float4 xv[4];
#pragma unroll
  for (int i = 0; i < 4; i++) xv[i] = xr[l + 64 * i];
  float part[NTOT];
#pragma unroll
  for (int e = 0; e < NTOT; e++) {
    const float4* wr = (const float4*)(rw + (size_t)e * HDIM);
    float s = 0.f;
#pragma unroll
    for (int i = 0; i < 4; i++) {
      float4 w = wr[l + 64 * i];
      s += xv[i].x * w.x + xv[i].y * w.y + xv[i].z * w.z + xv[i].w * w.w;
    }
    part[e] = s;
  }
#pragma unroll
  for (int off = 32; off > 0; off >>= 1)
#pragma unroll
    for (int e = 0; e < NTOT; e++) part[e] += __shfl_down(part[e], off);

  if (l == 0) {
    float mx = part[0];
#pragma unroll
    for (int e = 1; e < NTOT; e++) mx = fmaxf(mx, part[e]);
    float p[NTOT], den = 0.f;
#pragma unroll
    for (int e = 0; e < NTOT; e++) { p[e] = expf(part[e] - mx); den += p[e]; }
    float inv = 1.f / den;
#pragma unroll
    for (int e = 0; e < NTOT; e++) p[e] *= inv;
    // top-2 of p + bias (ties -> lowest index, matching lax.top_k)
    float s0 = -1e30f, s1 = -1e30f; int i0 = 0, i1 = 0;
#pragma unroll
    for (int e = 0; e < NTOT; e++) {
      float v = p[e] + bias[e];
      if (v > s0) { s1 = s0; i1 = i0; s0 = v; i0 = e; }
      else if (v > s1) { s1 = v; i1 = e; }
    }
    float comb[NEXP];
#pragma unroll
    for (int e = 0; e < NEXP; e++) comb[e] = 0.f;
    float zs = 0.f;
    int idx[2] = { i0, i1 };
#pragma unroll
    for (int k = 0; k < 2; k++) {
      int e = idx[k];
      float w = p[e];
      if (e >= NEXP) zs += w; else comb[e] += w;
    }
#pragma unroll
    for (int e = 0; e < NEXP; e++) combine[(size_t)t * NEXP + e] = comb[e];
    zscale[t] = zs;
  }
}

// ---------------- out = zero_scale * x ----------------
__global__ void init_out_kernel(const float* __restrict__ x, const float* __restrict__ zs,
                                float* __restrict__ out) {
  size_t gid = (size_t)blockIdx.x * blockDim.x + threadIdx.x;  // T*H/4 float4s
  size_t t = gid / (HDIM / 4);
  float4 v = ((const float4*)x)[gid];
  float s = zs[t];
  v.x *= s; v.y *= s; v.z *= s; v.w *= s;
  ((float4*)out)[gid] = v;
}

// ---------------- SiLU gating: act = silu(g)*u ----------------
__global__ void act_kernel(const bf16_t* __restrict__ h, bf16_t* __restrict__ act) {
  size_t gid = (size_t)blockIdx.x * blockDim.x + threadIdx.x;  // T*I/8 groups
  size_t t = gid >> 6;             // 64 groups of 8 per row (I=512)
  size_t j = (gid & 63) << 3;
  bf16x8 g8 = *(const bf16x8*)&h[t * (2 * IDIM) + j];
  bf16x8 u8 = *(const bf16x8*)&h[t * (2 * IDIM) + IDIM + j];
  bf16x8 o;
#pragma unroll
  for (int k = 0; k < 8; k++) {
    float g = (float)g8[k];
    float u = (float)u8[k];
    float s = g / (1.f + expf(-g));
    o[k] = (bf16_t)(s * u);
  }
  *(bf16x8*)&act[t * IDIM + j] = o;
}

// ---------------- NT GEMM: C[MxN] = A[MxK] * B[NxK]^T ----------------
// MODE 0: store bf16 C (stride N)
// MODE 1: out(fp32, stride N) += scale * combine[row*8+e] * acc  (skip zero rows)
template <int MODE>
__global__ __launch_bounds__(256) void gemm_nt(
    const bf16_t* __restrict__ A, const bf16_t* __restrict__ B,
    void* __restrict__ Cptr, int N, int K,
    const float* __restrict__ combine, int e, float scale) {
  __shared__ alignas(16) bf16_t As[128 * 32];
  __shared__ alignas(16) bf16_t Bs[128 * 32];
  const int m0 = blockIdx.x * 128;
  const int n0 = blockIdx.y * 128;
  const int tid = threadIdx.x;
  const int w = tid >> 6, l = tid & 63;
  const int wr = w >> 1, wc = w & 1;
  const int quad = l >> 4, c16 = l & 15;

  // staging: wave w stages tile rows [w*32, w*32+32), 16 rows / issue
  const int sr = w * 32 + (l >> 2);
  const int sc = (l & 3) * 8;
  const bf16_t* Ag0 = A + (size_t)(m0 + sr) * K + sc;
  const bf16_t* Bg0 = B + (size_t)(n0 + sr) * K + sc;
  bf16_t* Al0 = &As[(w * 32) * 32];
  bf16_t* Bl0 = &Bs[(w * 32) * 32];

  f32x4 acc[4][4];
#pragma unroll
  for (int i = 0; i < 4; i++)
#pragma unroll
    for (int j = 0; j < 4; j++) acc[i][j] = (f32x4){0.f, 0.f, 0.f, 0.f};

  for (int k0 = 0; k0 < K; k0 += 32) {
    gll16(Ag0 + k0, Al0);
    gll16(Ag0 + k0 + (size_t)16 * K, Al0 + 16 * 32);
    gll16(Bg0 + k0, Bl0);
    gll16(Bg0 + k0 + (size_t)16 * K, Bl0 + 16 * 32);
    __syncthreads();
    bf16x8 af[4], bfv[4];
#pragma unroll
    for (int mt = 0; mt < 4; mt++)
      af[mt] = *(const bf16x8*)&As[(wr * 64 + mt * 16 + c16) * 32 + quad * 8];
#pragma unroll
    for (int nt = 0; nt < 4; nt++)
      bfv[nt] = *(const bf16x8*)&Bs[(wc * 64 + nt * 16 + c16) * 32 + quad * 8];
#pragma unroll
    for (int mt = 0; mt < 4; mt++)
#pragma unroll
      for (int nt = 0; nt < 4; nt++)
        acc[mt][nt] = __builtin_amdgcn_mfma_f32_16x16x32_bf16(af[mt], bfv[nt], acc[mt][nt], 0, 0, 0);
    __syncthreads();
  }

  if (MODE == 0) {
    bf16_t* C = (bf16_t*)Cptr;
#pragma unroll
    for (int mt = 0; mt < 4; mt++) {
      int rowb = m0 + wr * 64 + mt * 16 + quad * 4;
#pragma unroll
      for (int nt = 0; nt < 4; nt++) {
        int col = n0 + wc * 64 + nt * 16 + c16;
#pragma unroll
        for (int r = 0; r < 4; r++)
          C[(size_t)(rowb + r) * N + col] = (bf16_t)acc[mt][nt][r];
      }
    }
  } else {
    float* O = (float*)Cptr;
#pragma unroll
    for (int mt = 0; mt < 4; mt++) {
      int rowb = m0 + wr * 64 + mt * 16 + quad * 4;
      float cw[4];
      bool any = false;
#pragma unroll
      for (int r = 0; r < 4; r++) {
        cw[r] = scale * combine[(size_t)(rowb + r) * NEXP + e];
        any = any || (cw[r] != 0.f);
      }
      if (!any) continue;
#pragma unroll
      for (int nt = 0; nt < 4; nt++) {
        int col = n0 + wc * 64 + nt * 16 + c16;
#pragma unroll
        for (int r = 0; r < 4; r++)
          if (cw[r] != 0.f)
            O[(size_t)(rowb + r) * N + col] += cw[r] * acc[mt][nt][r];
      }
    }
  }
}

extern "C" void kernel_launch(void* const* d_in, const int* in_sizes, int n_in,
                              void* d_out, int out_size, void* d_ws, size_t ws_size,
                              hipStream_t stream) {
  const float* x    = (const float*)d_in[0];  // [T, H]
  const float* rw   = (const float*)d_in[1];  // [12, H]
  const float* bias = (const float*)d_in[2];  // [12]
  const float* w13  = (const float*)d_in[3];  // [8, 2I, H]
  const float* w2   = (const float*)d_in[4];  // [8, H, I]
  float* out = (float*)d_out;                 // [T, H] fp32

  char* ws = (char*)d_ws;
  bf16_t* xb   = (bf16_t*)ws;  ws += (size_t)T_TOK * HDIM * 2;
  bf16_t* w13b = (bf16_t*)ws;  ws += (size_t)NEXP * 2 * IDIM * HDIM * 2;
  bf16_t* w2b  = (bf16_t*)ws;  ws += (size_t)NEXP * HDIM * IDIM * 2;
  bf16_t* hbuf = (bf16_t*)ws;  ws += (size_t)T_TOK * 2 * IDIM * 2;
  bf16_t* abuf = (bf16_t*)ws;  ws += (size_t)T_TOK * IDIM * 2;
  float* combine = (float*)ws; ws += (size_t)T_TOK * NEXP * 4;
  float* zscale  = (float*)ws; ws += (size_t)T_TOK * 4;

  // casts
  {
    size_t n8 = (size_t)T_TOK * HDIM / 8;
    cast_bf16_kernel<<<(n8 + 255) / 256, 256, 0, stream>>>(x, xb, n8);
    n8 = (size_t)NEXP * 2 * IDIM * HDIM / 8;
    cast_bf16_kernel<<<(n8 + 255) / 256, 256, 0, stream>>>(w13, w13b, n8);
    n8 = (size_t)NEXP * HDIM * IDIM / 8;
    cast_bf16_kernel<<<(n8 + 255) / 256, 256, 0, stream>>>(w2, w2b, n8);
  }
  // router
  router_kernel<<<T_TOK, 64, 0, stream>>>(x, rw, bias, combine, zscale);
  // out = zero_scale * x
  init_out_kernel<<<(size_t)T_TOK * HDIM / 4 / 256, 256, 0, stream>>>(x, zscale, out);

  // experts
  for (int e = 0; e < NEXP; e++) {
    gemm_nt<0><<<dim3(T_TOK / 128, (2 * IDIM) / 128), 256, 0, stream>>>(
        xb, w13b + (size_t)e * 2 * IDIM * HDIM, hbuf, 2 * IDIM, HDIM, nullptr, 0, 0.f);
    act_kernel<<<(size_t)T_TOK * IDIM / 8 / 256, 256, 0, stream>>>(hbuf, abuf);
    gemm_nt<1><<<dim3(T_TOK / 128, HDIM / 128), 256, 0, stream>>>(
        abuf, w2b + (size_t)e * HDIM * IDIM, out, HDIM, IDIM, combine, e, 2.5f);
  }
}

// Round 2
// 305.777 us; speedup vs baseline: 2.1270x; 2.1270x over previous
//
#include <hip/hip_runtime.h>
#include <hip/hip_bf16.h>
#include <math.h>

typedef __bf16 bf16_t;
typedef bf16_t bf16x8 __attribute__((ext_vector_type(8)));
typedef float f32x4 __attribute__((ext_vector_type(4)));

#define T_TOK 8192
#define HDIM  1024
#define IDIM  512
#define NEXP  8
#define NTOT  12
#define MAXROWS (2 * T_TOK + NEXP * 128)   // 17408: 128-padded expert regions

// ---------------- async global->LDS, 16B per lane ----------------
__device__ __forceinline__ void gll16(const bf16_t* g, bf16_t* l) {
  __builtin_amdgcn_global_load_lds((__attribute__((address_space(1))) void*)g,
                                   (__attribute__((address_space(3))) void*)l,
                                   16, 0, 0);
}

// ---------------- fp32 -> bf16 cast, 8 elems/thread ----------------
__global__ void cast_bf16_kernel(const float* __restrict__ in, bf16_t* __restrict__ out,
                                 size_t n8) {
  size_t gid = (size_t)blockIdx.x * blockDim.x + threadIdx.x;
  if (gid >= n8) return;
  size_t i = gid * 8;
  float4 a = *(const float4*)&in[i];
  float4 b = *(const float4*)&in[i + 4];
  bf16x8 o;
  o[0] = (bf16_t)a.x; o[1] = (bf16_t)a.y; o[2] = (bf16_t)a.z; o[3] = (bf16_t)a.w;
  o[4] = (bf16_t)b.x; o[5] = (bf16_t)b.y; o[6] = (bf16_t)b.z; o[7] = (bf16_t)b.w;
  *(bf16x8*)&out[i] = o;
}

// ---------------- router: one wave per token ----------------
// Emits per token: tk_e[2] (expert idx or -1 for zero-expert), tk_w[2], zscale.
__global__ void router_kernel(const float* __restrict__ x, const float* __restrict__ rw,
                              const float* __restrict__ bias,
                              int* __restrict__ tk_e, float* __restrict__ tk_w,
                              float* __restrict__ zscale) {
  int t = blockIdx.x;
  int l = threadIdx.x;
  const float4* xr = (const float4*)(x + (size_t)t * HDIM);
  float4 xv[4];
#pragma unroll
  for (int i = 0; i < 4; i++) xv[i] = xr[l + 64 * i];
  float part[NTOT];
#pragma unroll
  for (int e = 0; e < NTOT; e++) {
    const float4* wr = (const float4*)(rw + (size_t)e * HDIM);
    float s = 0.f;
#pragma unroll
    for (int i = 0; i < 4; i++) {
      float4 w = wr[l + 64 * i];
      s += xv[i].x * w.x + xv[i].y * w.y + xv[i].z * w.z + xv[i].w * w.w;
    }
    part[e] = s;
  }
#pragma unroll
  for (int off = 32; off > 0; off >>= 1)
#pragma unroll
    for (int e = 0; e < NTOT; e++) part[e] += __shfl_down(part[e], off);

  if (l == 0) {
    float mx = part[0];
#pragma unroll
    for (int e = 1; e < NTOT; e++) mx = fmaxf(mx, part[e]);
    float p[NTOT], den = 0.f;
#pragma unroll
    for (int e = 0; e < NTOT; e++) { p[e] = expf(part[e] - mx); den += p[e]; }
    float inv = 1.f / den;
#pragma unroll
    for (int e = 0; e < NTOT; e++) p[e] *= inv;
    float s0 = -1e30f, s1 = -1e30f; int i0 = 0, i1 = 0;
#pragma unroll
    for (int e = 0; e < NTOT; e++) {
      float v = p[e] + bias[e];
      if (v > s0) { s1 = s0; i1 = i0; s0 = v; i0 = e; }
      else if (v > s1) { s1 = v; i1 = e; }
    }
    float zs = 0.f;
    int idx[2] = { i0, i1 };
#pragma unroll
    for (int k = 0; k < 2; k++) {
      int e = idx[k];
      float w = p[e];
      if (e >= NEXP) { zs += w; tk_e[2 * t + k] = -1; tk_w[2 * t + k] = 0.f; }
      else           { tk_e[2 * t + k] = e; tk_w[2 * t + k] = w; }
    }
    zscale[t] = zs;
  }
}

// ---------------- zero init: counts + sel arrays ----------------
__global__ void zero_init_kernel(int* __restrict__ counts, int* __restrict__ sel_tok,
                                 float* __restrict__ sel_w) {
  int i = blockIdx.x * blockDim.x + threadIdx.x;
  if (i < MAXROWS) { sel_tok[i] = 0; sel_w[i] = 0.f; }
  if (i < NEXP) counts[i] = 0;
}

// ---------------- count: per-block LDS histogram ----------------
__global__ void count_kernel(const int* __restrict__ tk_e, int* __restrict__ counts) {
  __shared__ int lc[NEXP];
  int tid = threadIdx.x;
  if (tid < NEXP) lc[tid] = 0;
  __syncthreads();
  int t = blockIdx.x * blockDim.x + tid;
  int e0 = tk_e[2 * t], e1 = tk_e[2 * t + 1];
  if (e0 >= 0) atomicAdd(&lc[e0], 1);
  if (e1 >= 0) atomicAdd(&lc[e1], 1);
  __syncthreads();
  if (tid < NEXP) atomicAdd(&counts[tid], lc[tid]);
}

// ---------------- scan: 128-padded offsets ----------------
__global__ void scan_kernel(const int* __restrict__ counts, int* __restrict__ off_pad,
                            int* __restrict__ cursor, int* __restrict__ total_rows) {
  if (threadIdx.x == 0) {
    int run = 0;
    for (int e = 0; e < NEXP; e++) {
      off_pad[e] = run;
      cursor[e] = run;
      run += ((counts[e] + 127) / 128) * 128;
    }
    *total_rows = run;
  }
}

// ---------------- assign: scatter selections to positions ----------------
__global__ void assign_kernel(const int* __restrict__ tk_e, const float* __restrict__ tk_w,
                              int* __restrict__ cursor, int* __restrict__ sel_tok,
                              float* __restrict__ sel_w, int* __restrict__ pos) {
  __shared__ int lc[NEXP];
  __shared__ int lbase[NEXP];
  int tid = threadIdx.x;
  if (tid < NEXP) lc[tid] = 0;
  __syncthreads();
  int t = blockIdx.x * blockDim.x + tid;
  int e0 = tk_e[2 * t], e1 = tk_e[2 * t + 1];
  int r0 = (e0 >= 0) ? atomicAdd(&lc[e0], 1) : -1;
  int r1 = (e1 >= 0) ? atomicAdd(&lc[e1], 1) : -1;
  __syncthreads();
  if (tid < NEXP) lbase[tid] = atomicAdd(&cursor[tid], lc[tid]);
  __syncthreads();
  int p0 = -1, p1 = -1;
  if (e0 >= 0) { p0 = lbase[e0] + r0; sel_tok[p0] = t; sel_w[p0] = 2.5f * tk_w[2 * t]; }
  if (e1 >= 0) { p1 = lbase[e1] + r1; sel_tok[p1] = t; sel_w[p1] = 2.5f * tk_w[2 * t + 1]; }
  pos[2 * t] = p0;
  pos[2 * t + 1] = p1;
}

// ---------------- grouped GEMM1: h[p,:] = x[sel_tok[p],:] @ w13[e]^T ----------------
__global__ __launch_bounds__(256) void gemm1_kernel(
    const bf16_t* __restrict__ xb, const bf16_t* __restrict__ w13b,
    const int* __restrict__ sel_tok, const int* __restrict__ off_pad,
    const int* __restrict__ counts, bf16_t* __restrict__ hbuf) {
  const int e = blockIdx.z;
  const int cnt = counts[e];
  const int m0 = blockIdx.x * 128;
  if (m0 >= cnt) return;
  const int p0 = off_pad[e] + m0;
  const int n0 = blockIdx.y * 128;

  __shared__ alignas(16) bf16_t As[128 * 32];
  __shared__ alignas(16) bf16_t Bs[128 * 32];
  const int tid = threadIdx.x;
  const int w = tid >> 6, l = tid & 63;
  const int wr = w >> 1, wc = w & 1;
  const int quad = l >> 4, c16 = l & 15;

  const int sr = w * 32 + (l >> 2);
  const int sc = (l & 3) * 8;
  const int tok0 = sel_tok[p0 + sr];
  const int tok1 = sel_tok[p0 + sr + 16];
  const bf16_t* Ag0 = xb + (size_t)tok0 * HDIM + sc;
  const bf16_t* Ag1 = xb + (size_t)tok1 * HDIM + sc;
  const bf16_t* Bg0 = w13b + (size_t)e * (2 * IDIM) * HDIM + (size_t)(n0 + sr) * HDIM + sc;
  bf16_t* Al0 = &As[(w * 32) * 32];
  bf16_t* Bl0 = &Bs[(w * 32) * 32];

  f32x4 acc[4][4];
#pragma unroll
  for (int i = 0; i < 4; i++)
#pragma unroll
    for (int j = 0; j < 4; j++) acc[i][j] = (f32x4){0.f, 0.f, 0.f, 0.f};

  for (int k0 = 0; k0 < HDIM; k0 += 32) {
    gll16(Ag0 + k0, Al0);
    gll16(Ag1 + k0, Al0 + 16 * 32);
    gll16(Bg0 + k0, Bl0);
    gll16(Bg0 + k0 + (size_t)16 * HDIM, Bl0 + 16 * 32);
    __syncthreads();
    bf16x8 af[4], bfv[4];
#pragma unroll
    for (int mt = 0; mt < 4; mt++)
      af[mt] = *(const bf16x8*)&As[(wr * 64 + mt * 16 + c16) * 32 + quad * 8];
#pragma unroll
    for (int nt = 0; nt < 4; nt++)
      bfv[nt] = *(const bf16x8*)&Bs[(wc * 64 + nt * 16 + c16) * 32 + quad * 8];
#pragma unroll
    for (int mt = 0; mt < 4; mt++)
#pragma unroll
      for (int nt = 0; nt < 4; nt++)
        acc[mt][nt] = __builtin_amdgcn_mfma_f32_16x16x32_bf16(af[mt], bfv[nt], acc[mt][nt], 0, 0, 0);
    __syncthreads();
  }

#pragma unroll
  for (int mt = 0; mt < 4; mt++) {
    int rowb = wr * 64 + mt * 16 + quad * 4;
#pragma unroll
    for (int nt = 0; nt < 4; nt++) {
      int col = n0 + wc * 64 + nt * 16 + c16;
#pragma unroll
      for (int r = 0; r < 4; r++)
        hbuf[(size_t)(p0 + rowb + r) * (2 * IDIM) + col] = (bf16_t)acc[mt][nt][r];
    }
  }
}

// ---------------- SiLU gating over selection rows ----------------
__global__ void act_kernel(const bf16_t* __restrict__ h, bf16_t* __restrict__ act,
                           const int* __restrict__ total_rows) {
  size_t gid = (size_t)blockIdx.x * blockDim.x + threadIdx.x;
  size_t p = gid >> 6;              // 64 groups of 8 per row (I=512)
  if (p >= (size_t)*total_rows) return;
  size_t j = (gid & 63) << 3;
  bf16x8 g8 = *(const bf16x8*)&h[p * (2 * IDIM) + j];
  bf16x8 u8 = *(const bf16x8*)&h[p * (2 * IDIM) + IDIM + j];
  bf16x8 o;
#pragma unroll
  for (int k = 0; k < 8; k++) {
    float g = (float)g8[k];
    float u = (float)u8[k];
    float s = g / (1.f + expf(-g));
    o[k] = (bf16_t)(s * u);
  }
  *(bf16x8*)&act[p * IDIM + j] = o;
}

// ---------------- grouped GEMM2: eo[p,:] = sel_w[p] * (act[p,:] @ w2[e]^T) ----------------
__global__ __launch_bounds__(256) void gemm2_kernel(
    const bf16_t* __restrict__ actb, const bf16_t* __restrict__ w2b,
    const float* __restrict__ sel_w, const int* __restrict__ off_pad,
    const int* __restrict__ counts, bf16_t* __restrict__ eob) {
  const int e = blockIdx.z;
  const int cnt = counts[e];
  const int m0 = blockIdx.x * 128;
  if (m0 >= cnt) return;
  const int p0 = off_pad[e] + m0;
  const int n0 = blockIdx.y * 128;

  __shared__ alignas(16) bf16_t As[128 * 32];
  __shared__ alignas(16) bf16_t Bs[128 * 32];
  const int tid = threadIdx.x;
  const int w = tid >> 6, l = tid & 63;
  const int wr = w >> 1, wc = w & 1;
  const int quad = l >> 4, c16 = l & 15;

  const int sr = w * 32 + (l >> 2);
  const int sc = (l & 3) * 8;
  const bf16_t* Ag0 = actb + (size_t)(p0 + sr) * IDIM + sc;
  const bf16_t* Bg0 = w2b + (size_t)e * HDIM * IDIM + (size_t)(n0 + sr) * IDIM + sc;
  bf16_t* Al0 = &As[(w * 32) * 32];
  bf16_t* Bl0 = &Bs[(w * 32) * 32];

  f32x4 acc[4][4];
#pragma unroll
  for (int i = 0; i < 4; i++)
#pragma unroll
    for (int j = 0; j < 4; j++) acc[i][j] = (f32x4){0.f, 0.f, 0.f, 0.f};

  for (int k0 = 0; k0 < IDIM; k0 += 32) {
    gll16(Ag0 + k0, Al0);
    gll16(Ag0 + k0 + (size_t)16 * IDIM, Al0 + 16 * 32);
    gll16(Bg0 + k0, Bl0);
    gll16(Bg0 + k0 + (size_t)16 * IDIM, Bl0 + 16 * 32);
    __syncthreads();
    bf16x8 af[4], bfv[4];
#pragma unroll
    for (int mt = 0; mt < 4; mt++)
      af[mt] = *(const bf16x8*)&As[(wr * 64 + mt * 16 + c16) * 32 + quad * 8];
#pragma unroll
    for (int nt = 0; nt < 4; nt++)
      bfv[nt] = *(const bf16x8*)&Bs[(wc * 64 + nt * 16 + c16) * 32 + quad * 8];
#pragma unroll
    for (int mt = 0; mt < 4; mt++)
#pragma unroll
      for (int nt = 0; nt < 4; nt++)
        acc[mt][nt] = __builtin_amdgcn_mfma_f32_16x16x32_bf16(af[mt], bfv[nt], acc[mt][nt], 0, 0, 0);
    __syncthreads();
  }

#pragma unroll
  for (int mt = 0; mt < 4; mt++) {
    int rowb = wr * 64 + mt * 16 + quad * 4;
    float cw[4];
#pragma unroll
    for (int r = 0; r < 4; r++) cw[r] = sel_w[p0 + rowb + r];
#pragma unroll
    for (int nt = 0; nt < 4; nt++) {
      int col = n0 + wc * 64 + nt * 16 + c16;
#pragma unroll
      for (int r = 0; r < 4; r++)
        eob[(size_t)(p0 + rowb + r) * HDIM + col] = (bf16_t)(cw[r] * acc[mt][nt][r]);
    }
  }
}

// ---------------- final combine: out = zscale*x + eo[pos0] + eo[pos1] ----------------
__global__ void combine_kernel(const float* __restrict__ x, const float* __restrict__ zscale,
                               const int* __restrict__ pos, const bf16_t* __restrict__ eob,
                               float* __restrict__ out) {
  size_t gid = (size_t)blockIdx.x * blockDim.x + threadIdx.x;  // T * H/8
  size_t t = gid >> 7;
  size_t j = (gid & 127) << 3;
  float zs = zscale[t];
  int p0 = pos[2 * t], p1 = pos[2 * t + 1];
  float4 a = *(const float4*)&x[t * HDIM + j];
  float4 b = *(const float4*)&x[t * HDIM + j + 4];
  float o[8] = { zs * a.x, zs * a.y, zs * a.z, zs * a.w,
                 zs * b.x, zs * b.y, zs * b.z, zs * b.w };
  if (p0 >= 0) {
    bf16x8 v = *(const bf16x8*)&eob[(size_t)p0 * HDIM + j];
#pragma unroll
    for (int k = 0; k < 8; k++) o[k] += (float)v[k];
  }
  if (p1 >= 0) {
    bf16x8 v = *(const bf16x8*)&eob[(size_t)p1 * HDIM + j];
#pragma unroll
    for (int k = 0; k < 8; k++) o[k] += (float)v[k];
  }
  *(float4*)&out[t * HDIM + j] = make_float4(o[0], o[1], o[2], o[3]);
  *(float4*)&out[t * HDIM + j + 4] = make_float4(o[4], o[5], o[6], o[7]);
}

extern "C" void kernel_launch(void* const* d_in, const int* in_sizes, int n_in,
                              void* d_out, int out_size, void* d_ws, size_t ws_size,
                              hipStream_t stream) {
  const float* x    = (const float*)d_in[0];
  const float* rw   = (const float*)d_in[1];
  const float* bias = (const float*)d_in[2];
  const float* w13  = (const float*)d_in[3];
  const float* w2   = (const float*)d_in[4];
  float* out = (float*)d_out;

  char* ws = (char*)d_ws;
  bf16_t* xb   = (bf16_t*)ws;  ws += (size_t)T_TOK * HDIM * 2;
  bf16_t* w13b = (bf16_t*)ws;  ws += (size_t)NEXP * 2 * IDIM * HDIM * 2;
  bf16_t* w2b  = (bf16_t*)ws;  ws += (size_t)NEXP * HDIM * IDIM * 2;
  bf16_t* hbuf = (bf16_t*)ws;  ws += (size_t)MAXROWS * 2 * IDIM * 2;
  bf16_t* actb = (bf16_t*)ws;  ws += (size_t)MAXROWS * IDIM * 2;
  bf16_t* eob  = (bf16_t*)ws;  ws += (size_t)MAXROWS * HDIM * 2;
  int*   tk_e    = (int*)ws;   ws += (size_t)T_TOK * 2 * 4;
  float* tk_w    = (float*)ws; ws += (size_t)T_TOK * 2 * 4;
  float* zscale  = (float*)ws; ws += (size_t)T_TOK * 4;
  int*   pos     = (int*)ws;   ws += (size_t)T_TOK * 2 * 4;
  int*   sel_tok = (int*)ws;   ws += (size_t)MAXROWS * 4;
  float* sel_w   = (float*)ws; ws += (size_t)MAXROWS * 4;
  int*   counts  = (int*)ws;   ws += NEXP * 4;
  int*   off_pad = (int*)ws;   ws += NEXP * 4;
  int*   cursor  = (int*)ws;   ws += NEXP * 4;
  int*   total_rows = (int*)ws; ws += 4;

  // casts
  {
    size_t n8 = (size_t)T_TOK * HDIM / 8;
    cast_bf16_kernel<<<(n8 + 255) / 256, 256, 0, stream>>>(x, xb, n8);
    n8 = (size_t)NEXP * 2 * IDIM * HDIM / 8;
    cast_bf16_kernel<<<(n8 + 255) / 256, 256, 0, stream>>>(w13, w13b, n8);
    n8 = (size_t)NEXP * HDIM * IDIM / 8;
    cast_bf16_kernel<<<(n8 + 255) / 256, 256, 0, stream>>>(w2, w2b, n8);
  }
  // routing pipeline
  router_kernel<<<T_TOK, 64, 0, stream>>>(x, rw, bias, tk_e, tk_w, zscale);
  zero_init_kernel<<<(MAXROWS + 255) / 256, 256, 0, stream>>>(counts, sel_tok, sel_w);
  count_kernel<<<T_TOK / 256, 256, 0, stream>>>(tk_e, counts);
  scan_kernel<<<1, 64, 0, stream>>>(counts, off_pad, cursor, total_rows);
  assign_kernel<<<T_TOK / 256, 256, 0, stream>>>(tk_e, tk_w, cursor, sel_tok, sel_w, pos);

  // grouped expert MLP (worst-case grid, dead tiles early-exit)
  gemm1_kernel<<<dim3(T_TOK / 128, (2 * IDIM) / 128, NEXP), 256, 0, stream>>>(
      xb, w13b, sel_tok, off_pad, counts, hbuf);
  act_kernel<<<((size_t)MAXROWS * IDIM / 8 + 255) / 256, 256, 0, stream>>>(hbuf, actb, total_rows);
  gemm2_kernel<<<dim3(T_TOK / 128, HDIM / 128, NEXP), 256, 0, stream>>>(
      actb, w2b, sel_w, off_pad, counts, eob);

  // out = zscale*x + routed contributions
  combine_kernel<<<(size_t)T_TOK * HDIM / 8 / 256, 256, 0, stream>>>(
      x, zscale, pos, eob, out);
}

// Round 3
// 297.650 us; speedup vs baseline: 2.1851x; 1.0273x over previous
//
#include <hip/hip_runtime.h>
#include <hip/hip_bf16.h>
#include <math.h>

typedef __bf16 bf16_t;
typedef bf16_t bf16x8 __attribute__((ext_vector_type(8)));
typedef float f32x4 __attribute__((ext_vector_type(4)));

#define T_TOK 8192
#define HDIM  1024
#define IDIM  512
#define NEXP  8
#define NTOT  12
#define MAXROWS (2 * T_TOK + NEXP * 128)   // 17408: 128-padded expert regions

// ---------------- async global->LDS, 16B per lane ----------------
__device__ __forceinline__ void gll16(const bf16_t* g, bf16_t* l) {
  __builtin_amdgcn_global_load_lds((__attribute__((address_space(1))) void*)g,
                                   (__attribute__((address_space(3))) void*)l,
                                   16, 0, 0);
}

// ---------------- fp32 -> bf16 cast, 8 elems/thread ----------------
__global__ void cast_bf16_kernel(const float* __restrict__ in, bf16_t* __restrict__ out,
                                 size_t n8) {
  size_t gid = (size_t)blockIdx.x * blockDim.x + threadIdx.x;
  if (gid >= n8) return;
  size_t i = gid * 8;
  float4 a = *(const float4*)&in[i];
  float4 b = *(const float4*)&in[i + 4];
  bf16x8 o;
  o[0] = (bf16_t)a.x; o[1] = (bf16_t)a.y; o[2] = (bf16_t)a.z; o[3] = (bf16_t)a.w;
  o[4] = (bf16_t)b.x; o[5] = (bf16_t)b.y; o[6] = (bf16_t)b.z; o[7] = (bf16_t)b.w;
  *(bf16x8*)&out[i] = o;
}

// ---------------- router: one wave per token ----------------
__global__ void router_kernel(const float* __restrict__ x, const float* __restrict__ rw,
                              const float* __restrict__ bias,
                              int* __restrict__ tk_e, float* __restrict__ tk_w,
                              float* __restrict__ zscale) {
  int t = blockIdx.x;
  int l = threadIdx.x;
  const float4* xr = (const float4*)(x + (size_t)t * HDIM);
  float4 xv[4];
#pragma unroll
  for (int i = 0; i < 4; i++) xv[i] = xr[l + 64 * i];
  float part[NTOT];
#pragma unroll
  for (int e = 0; e < NTOT; e++) {
    const float4* wr = (const float4*)(rw + (size_t)e * HDIM);
    float s = 0.f;
#pragma unroll
    for (int i = 0; i < 4; i++) {
      float4 w = wr[l + 64 * i];
      s += xv[i].x * w.x + xv[i].y * w.y + xv[i].z * w.z + xv[i].w * w.w;
    }
    part[e] = s;
  }
#pragma unroll
  for (int off = 32; off > 0; off >>= 1)
#pragma unroll
    for (int e = 0; e < NTOT; e++) part[e] += __shfl_down(part[e], off);

  if (l == 0) {
    float mx = part[0];
#pragma unroll
    for (int e = 1; e < NTOT; e++) mx = fmaxf(mx, part[e]);
    float p[NTOT], den = 0.f;
#pragma unroll
    for (int e = 0; e < NTOT; e++) { p[e] = expf(part[e] - mx); den += p[e]; }
    float inv = 1.f / den;
#pragma unroll
    for (int e = 0; e < NTOT; e++) p[e] *= inv;
    float s0 = -1e30f, s1 = -1e30f; int i0 = 0, i1 = 0;
#pragma unroll
    for (int e = 0; e < NTOT; e++) {
      float v = p[e] + bias[e];
      if (v > s0) { s1 = s0; i1 = i0; s0 = v; i0 = e; }
      else if (v > s1) { s1 = v; i1 = e; }
    }
    float zs = 0.f;
    int idx[2] = { i0, i1 };
#pragma unroll
    for (int k = 0; k < 2; k++) {
      int e = idx[k];
      float w = p[e];
      if (e >= NEXP) { zs += w; tk_e[2 * t + k] = -1; tk_w[2 * t + k] = 0.f; }
      else           { tk_e[2 * t + k] = e; tk_w[2 * t + k] = w; }
    }
    zscale[t] = zs;
  }
}

// ---------------- zero init ----------------
__global__ void zero_init_kernel(int* __restrict__ counts, int* __restrict__ sel_tok,
                                 float* __restrict__ sel_w) {
  int i = blockIdx.x * blockDim.x + threadIdx.x;
  if (i < MAXROWS) { sel_tok[i] = 0; sel_w[i] = 0.f; }
  if (i < NEXP) counts[i] = 0;
}

// ---------------- count ----------------
__global__ void count_kernel(const int* __restrict__ tk_e, int* __restrict__ counts) {
  __shared__ int lc[NEXP];
  int tid = threadIdx.x;
  if (tid < NEXP) lc[tid] = 0;
  __syncthreads();
  int t = blockIdx.x * blockDim.x + tid;
  int e0 = tk_e[2 * t], e1 = tk_e[2 * t + 1];
  if (e0 >= 0) atomicAdd(&lc[e0], 1);
  if (e1 >= 0) atomicAdd(&lc[e1], 1);
  __syncthreads();
  if (tid < NEXP) atomicAdd(&counts[tid], lc[tid]);
}

// ---------------- scan: 128-padded offsets ----------------
__global__ void scan_kernel(const int* __restrict__ counts, int* __restrict__ off_pad,
                            int* __restrict__ cursor, int* __restrict__ total_rows) {
  if (threadIdx.x == 0) {
    int run = 0;
    for (int e = 0; e < NEXP; e++) {
      off_pad[e] = run;
      cursor[e] = run;
      run += ((counts[e] + 127) / 128) * 128;
    }
    *total_rows = run;
  }
}

// ---------------- assign ----------------
__global__ void assign_kernel(const int* __restrict__ tk_e, const float* __restrict__ tk_w,
                              int* __restrict__ cursor, int* __restrict__ sel_tok,
                              float* __restrict__ sel_w, int* __restrict__ pos) {
  __shared__ int lc[NEXP];
  __shared__ int lbase[NEXP];
  int tid = threadIdx.x;
  if (tid < NEXP) lc[tid] = 0;
  __syncthreads();
  int t = blockIdx.x * blockDim.x + tid;
  int e0 = tk_e[2 * t], e1 = tk_e[2 * t + 1];
  int r0 = (e0 >= 0) ? atomicAdd(&lc[e0], 1) : -1;
  int r1 = (e1 >= 0) ? atomicAdd(&lc[e1], 1) : -1;
  __syncthreads();
  if (tid < NEXP) lbase[tid] = atomicAdd(&cursor[tid], lc[tid]);
  __syncthreads();
  int p0 = -1, p1 = -1;
  if (e0 >= 0) { p0 = lbase[e0] + r0; sel_tok[p0] = t; sel_w[p0] = 2.5f * tk_w[2 * t]; }
  if (e1 >= 0) { p1 = lbase[e1] + r1; sel_tok[p1] = t; sel_w[p1] = 2.5f * tk_w[2 * t + 1]; }
  pos[2 * t] = p0;
  pos[2 * t + 1] = p1;
}

// ---------------- gather+cast: xg[p,:] = bf16(x[sel_tok[p],:]) ----------------
__global__ void gather_cast_kernel(const float* __restrict__ x, const int* __restrict__ sel_tok,
                                   const int* __restrict__ total_rows, bf16_t* __restrict__ xg) {
  size_t gid = (size_t)blockIdx.x * blockDim.x + threadIdx.x;  // MAXROWS * H/8
  size_t p = gid >> 7;
  if (p >= (size_t)*total_rows) return;
  size_t j = (gid & 127) << 3;
  int t = sel_tok[p];
  float4 a = *(const float4*)&x[(size_t)t * HDIM + j];
  float4 b = *(const float4*)&x[(size_t)t * HDIM + j + 4];
  bf16x8 o;
  o[0] = (bf16_t)a.x; o[1] = (bf16_t)a.y; o[2] = (bf16_t)a.z; o[3] = (bf16_t)a.w;
  o[4] = (bf16_t)b.x; o[5] = (bf16_t)b.y; o[6] = (bf16_t)b.z; o[7] = (bf16_t)b.w;
  *(bf16x8*)&xg[p * HDIM + j] = o;
}

// ---------------- fused GEMM1+SiLU: actb[p, g0..g0+64) ----------------
// B-tile row r -> w13 row: wc_s=r>>6, q=(r>>4)&3, c=r&15
//   col = g0 + wc_s*32 + (q&1)*16 + c  (+512 if q>=2, i.e. the "up" half)
// so wave wc's acc[mt][nt] (nt<2) = gate, acc[mt][nt+2] = matching up, same lane.
__global__ __launch_bounds__(256) void gemm1_kernel(
    const bf16_t* __restrict__ xg, const bf16_t* __restrict__ w13b,
    const int* __restrict__ off_pad, const int* __restrict__ counts,
    bf16_t* __restrict__ actb) {
  const int e = blockIdx.z;
  const int cnt = counts[e];
  const int m0 = blockIdx.x * 128;
  if (m0 >= cnt) return;
  const int p0 = off_pad[e] + m0;
  const int g0 = blockIdx.y * 64;

  __shared__ alignas(16) bf16_t As[128 * 32];
  __shared__ alignas(16) bf16_t Bs[128 * 32];
  const int tid = threadIdx.x;
  const int w = tid >> 6, l = tid & 63;
  const int wr = w >> 1, wc = w & 1;
  const int quad = l >> 4, c16 = l & 15;

  const int sr = w * 32 + (l >> 2);
  const int sc = (l & 3) * 8;
  const bf16_t* Ag0 = xg + (size_t)(p0 + sr) * HDIM + sc;
  const bf16_t* w13e = w13b + (size_t)e * (2 * IDIM) * HDIM;
  // per-lane permuted B row pointers for rows sr and sr+16
  int r0 = sr, r1 = sr + 16;
  int col0 = g0 + (r0 >> 6) * 32 + (((r0 >> 4) & 1) * 16) + (r0 & 15) + (((r0 >> 5) & 1) ? IDIM : 0);
  int col1 = g0 + (r1 >> 6) * 32 + (((r1 >> 4) & 1) * 16) + (r1 & 15) + (((r1 >> 5) & 1) ? IDIM : 0);
  const bf16_t* Bg0 = w13e + (size_t)col0 * HDIM + sc;
  const bf16_t* Bg1 = w13e + (size_t)col1 * HDIM + sc;
  bf16_t* Al0 = &As[(w * 32) * 32];
  bf16_t* Bl0 = &Bs[(w * 32) * 32];

  f32x4 acc[4][4];
#pragma unroll
  for (int i = 0; i < 4; i++)
#pragma unroll
    for (int j = 0; j < 4; j++) acc[i][j] = (f32x4){0.f, 0.f, 0.f, 0.f};

  for (int k0 = 0; k0 < HDIM; k0 += 32) {
    gll16(Ag0 + k0, Al0);
    gll16(Ag0 + k0 + (size_t)16 * HDIM, Al0 + 16 * 32);
    gll16(Bg0 + k0, Bl0);
    gll16(Bg1 + k0, Bl0 + 16 * 32);
    __syncthreads();
    bf16x8 af[4], bfv[4];
#pragma unroll
    for (int mt = 0; mt < 4; mt++)
      af[mt] = *(const bf16x8*)&As[(wr * 64 + mt * 16 + c16) * 32 + quad * 8];
#pragma unroll
    for (int nt = 0; nt < 4; nt++)
      bfv[nt] = *(const bf16x8*)&Bs[(wc * 64 + nt * 16 + c16) * 32 + quad * 8];
#pragma unroll
    for (int mt = 0; mt < 4; mt++)
#pragma unroll
      for (int nt = 0; nt < 4; nt++)
        acc[mt][nt] = __builtin_amdgcn_mfma_f32_16x16x32_bf16(af[mt], bfv[nt], acc[mt][nt], 0, 0, 0);
    __syncthreads();
  }

  // epilogue: act = silu(gate) * up, written bf16
#pragma unroll
  for (int mt = 0; mt < 4; mt++) {
    int rowb = p0 + wr * 64 + mt * 16 + quad * 4;
#pragma unroll
    for (int nt = 0; nt < 2; nt++) {
      int col = g0 + wc * 32 + nt * 16 + c16;
#pragma unroll
      for (int r = 0; r < 4; r++) {
        float g = acc[mt][nt][r];
        float u = acc[mt][nt + 2][r];
        float s = g / (1.f + expf(-g));
        actb[(size_t)(rowb + r) * IDIM + col] = (bf16_t)(s * u);
      }
    }
  }
}

// ---------------- GEMM2: eo[p,:] = sel_w[p] * (act[p,:] @ w2[e]^T) ----------------
__global__ __launch_bounds__(256) void gemm2_kernel(
    const bf16_t* __restrict__ actb, const bf16_t* __restrict__ w2b,
    const float* __restrict__ sel_w, const int* __restrict__ off_pad,
    const int* __restrict__ counts, bf16_t* __restrict__ eob) {
  const int e = blockIdx.z;
  const int cnt = counts[e];
  const int m0 = blockIdx.x * 128;
  if (m0 >= cnt) return;
  const int p0 = off_pad[e] + m0;
  const int n0 = blockIdx.y * 128;

  __shared__ alignas(16) bf16_t As[128 * 32];
  __shared__ alignas(16) bf16_t Bs[128 * 32];
  const int tid = threadIdx.x;
  const int w = tid >> 6, l = tid & 63;
  const int wr = w >> 1, wc = w & 1;
  const int quad = l >> 4, c16 = l & 15;

  const int sr = w * 32 + (l >> 2);
  const int sc = (l & 3) * 8;
  const bf16_t* Ag0 = actb + (size_t)(p0 + sr) * IDIM + sc;
  const bf16_t* Bg0 = w2b + (size_t)e * HDIM * IDIM + (size_t)(n0 + sr) * IDIM + sc;
  bf16_t* Al0 = &As[(w * 32) * 32];
  bf16_t* Bl0 = &Bs[(w * 32) * 32];

  f32x4 acc[4][4];
#pragma unroll
  for (int i = 0; i < 4; i++)
#pragma unroll
    for (int j = 0; j < 4; j++) acc[i][j] = (f32x4){0.f, 0.f, 0.f, 0.f};

  for (int k0 = 0; k0 < IDIM; k0 += 32) {
    gll16(Ag0 + k0, Al0);
    gll16(Ag0 + k0 + (size_t)16 * IDIM, Al0 + 16 * 32);
    gll16(Bg0 + k0, Bl0);
    gll16(Bg0 + k0 + (size_t)16 * IDIM, Bl0 + 16 * 32);
    __syncthreads();
    bf16x8 af[4], bfv[4];
#pragma unroll
    for (int mt = 0; mt < 4; mt++)
      af[mt] = *(const bf16x8*)&As[(wr * 64 + mt * 16 + c16) * 32 + quad * 8];
#pragma unroll
    for (int nt = 0; nt < 4; nt++)
      bfv[nt] = *(const bf16x8*)&Bs[(wc * 64 + nt * 16 + c16) * 32 + quad * 8];
#pragma unroll
    for (int mt = 0; mt < 4; mt++)
#pragma unroll
      for (int nt = 0; nt < 4; nt++)
        acc[mt][nt] = __builtin_amdgcn_mfma_f32_16x16x32_bf16(af[mt], bfv[nt], acc[mt][nt], 0, 0, 0);
    __syncthreads();
  }

#pragma unroll
  for (int mt = 0; mt < 4; mt++) {
    int rowb = wr * 64 + mt * 16 + quad * 4;
    float cw[4];
#pragma unroll
    for (int r = 0; r < 4; r++) cw[r] = sel_w[p0 + rowb + r];
#pragma unroll
    for (int nt = 0; nt < 4; nt++) {
      int col = n0 + wc * 64 + nt * 16 + c16;
#pragma unroll
      for (int r = 0; r < 4; r++)
        eob[(size_t)(p0 + rowb + r) * HDIM + col] = (bf16_t)(cw[r] * acc[mt][nt][r]);
    }
  }
}

// ---------------- final combine ----------------
__global__ void combine_kernel(const float* __restrict__ x, const float* __restrict__ zscale,
                               const int* __restrict__ pos, const bf16_t* __restrict__ eob,
                               float* __restrict__ out) {
  size_t gid = (size_t)blockIdx.x * blockDim.x + threadIdx.x;  // T * H/8
  size_t t = gid >> 7;
  size_t j = (gid & 127) << 3;
  float zs = zscale[t];
  int p0 = pos[2 * t], p1 = pos[2 * t + 1];
  float4 a = *(const float4*)&x[t * HDIM + j];
  float4 b = *(const float4*)&x[t * HDIM + j + 4];
  float o[8] = { zs * a.x, zs * a.y, zs * a.z, zs * a.w,
                 zs * b.x, zs * b.y, zs * b.z, zs * b.w };
  if (p0 >= 0) {
    bf16x8 v = *(const bf16x8*)&eob[(size_t)p0 * HDIM + j];
#pragma unroll
    for (int k = 0; k < 8; k++) o[k] += (float)v[k];
  }
  if (p1 >= 0) {
    bf16x8 v = *(const bf16x8*)&eob[(size_t)p1 * HDIM + j];
#pragma unroll
    for (int k = 0; k < 8; k++) o[k] += (float)v[k];
  }
  *(float4*)&out[t * HDIM + j] = make_float4(o[0], o[1], o[2], o[3]);
  *(float4*)&out[t * HDIM + j + 4] = make_float4(o[4], o[5], o[6], o[7]);
}

extern "C" void kernel_launch(void* const* d_in, const int* in_sizes, int n_in,
                              void* d_out, int out_size, void* d_ws, size_t ws_size,
                              hipStream_t stream) {
  const float* x    = (const float*)d_in[0];
  const float* rw   = (const float*)d_in[1];
  const float* bias = (const float*)d_in[2];
  const float* w13  = (const float*)d_in[3];
  const float* w2   = (const float*)d_in[4];
  float* out = (float*)d_out;

  char* ws = (char*)d_ws;
  bf16_t* w13b = (bf16_t*)ws;  ws += (size_t)NEXP * 2 * IDIM * HDIM * 2;
  bf16_t* w2b  = (bf16_t*)ws;  ws += (size_t)NEXP * HDIM * IDIM * 2;
  bf16_t* xg   = (bf16_t*)ws;  ws += (size_t)MAXROWS * HDIM * 2;
  bf16_t* actb = (bf16_t*)ws;  ws += (size_t)MAXROWS * IDIM * 2;
  bf16_t* eob  = (bf16_t*)ws;  ws += (size_t)MAXROWS * HDIM * 2;
  int*   tk_e    = (int*)ws;   ws += (size_t)T_TOK * 2 * 4;
  float* tk_w    = (float*)ws; ws += (size_t)T_TOK * 2 * 4;
  float* zscale  = (float*)ws; ws += (size_t)T_TOK * 4;
  int*   pos     = (int*)ws;   ws += (size_t)T_TOK * 2 * 4;
  int*   sel_tok = (int*)ws;   ws += (size_t)MAXROWS * 4;
  float* sel_w   = (float*)ws; ws += (size_t)MAXROWS * 4;
  int*   counts  = (int*)ws;   ws += NEXP * 4;
  int*   off_pad = (int*)ws;   ws += NEXP * 4;
  int*   cursor  = (int*)ws;   ws += NEXP * 4;
  int*   total_rows = (int*)ws; ws += 4;

  // weight casts (independent of routing)
  {
    size_t n8 = (size_t)NEXP * 2 * IDIM * HDIM / 8;
    cast_bf16_kernel<<<(n8 + 255) / 256, 256, 0, stream>>>(w13, w13b, n8);
    n8 = (size_t)NEXP * HDIM * IDIM / 8;
    cast_bf16_kernel<<<(n8 + 255) / 256, 256, 0, stream>>>(w2, w2b, n8);
  }
  // routing pipeline
  router_kernel<<<T_TOK, 64, 0, stream>>>(x, rw, bias, tk_e, tk_w, zscale);
  zero_init_kernel<<<(MAXROWS + 255) / 256, 256, 0, stream>>>(counts, sel_tok, sel_w);
  count_kernel<<<T_TOK / 256, 256, 0, stream>>>(tk_e, counts);
  scan_kernel<<<1, 64, 0, stream>>>(counts, off_pad, cursor, total_rows);
  assign_kernel<<<T_TOK / 256, 256, 0, stream>>>(tk_e, tk_w, cursor, sel_tok, sel_w, pos);
  // token gather+cast (sequentializes gemm1's A reads)
  gather_cast_kernel<<<(size_t)MAXROWS * (HDIM / 8) / 256, 256, 0, stream>>>(
      x, sel_tok, total_rows, xg);

  // fused GEMM1 + SiLU-gate (writes actb directly)
  gemm1_kernel<<<dim3(T_TOK / 128, IDIM / 64, NEXP), 256, 0, stream>>>(
      xg, w13b, off_pad, counts, actb);
  // GEMM2 with per-row weight scale
  gemm2_kernel<<<dim3(T_TOK / 128, HDIM / 128, NEXP), 256, 0, stream>>>(
      actb, w2b, sel_w, off_pad, counts, eob);

  // out = zscale*x + routed contributions
  combine_kernel<<<(size_t)T_TOK * HDIM / 8 / 256, 256, 0, stream>>>(
      x, zscale, pos, eob, out);
}

// Round 4
// 235.927 us; speedup vs baseline: 2.7568x; 1.2616x over previous
//
#include <hip/hip_runtime.h>
#include <hip/hip_bf16.h>
#include <math.h>

typedef __bf16 bf16_t;
typedef bf16_t bf16x8 __attribute__((ext_vector_type(8)));
typedef float f32x4 __attribute__((ext_vector_type(4)));

#define T_TOK 8192
#define HDIM  1024
#define IDIM  512
#define NEXP  8
#define NTOT  12
#define MAXROWS (2 * T_TOK + NEXP * 128)   // 17408: 128-padded expert regions
#define MAX_MTILES (MAXROWS / 128)         // 136

// ---------------- async global->LDS, 16B per lane ----------------
__device__ __forceinline__ void gll16(const bf16_t* g, bf16_t* l) {
  __builtin_amdgcn_global_load_lds((__attribute__((address_space(1))) void*)g,
                                   (__attribute__((address_space(3))) void*)l,
                                   16, 0, 0);
}

// ---------------- fp32 -> bf16 cast, 8 elems/thread ----------------
__global__ void cast_bf16_kernel(const float* __restrict__ in, bf16_t* __restrict__ out,
                                 size_t n8) {
  size_t gid = (size_t)blockIdx.x * blockDim.x + threadIdx.x;
  if (gid >= n8) return;
  size_t i = gid * 8;
  float4 a = *(const float4*)&in[i];
  float4 b = *(const float4*)&in[i + 4];
  bf16x8 o;
  o[0] = (bf16_t)a.x; o[1] = (bf16_t)a.y; o[2] = (bf16_t)a.z; o[3] = (bf16_t)a.w;
  o[4] = (bf16_t)b.x; o[5] = (bf16_t)b.y; o[6] = (bf16_t)b.z; o[7] = (bf16_t)b.w;
  *(bf16x8*)&out[i] = o;
}

// ---------------- router: one wave per token ----------------
__global__ void router_kernel(const float* __restrict__ x, const float* __restrict__ rw,
                              const float* __restrict__ bias,
                              int* __restrict__ tk_e, float* __restrict__ tk_w,
                              float* __restrict__ zscale) {
  int t = blockIdx.x;
  int l = threadIdx.x;
  const float4* xr = (const float4*)(x + (size_t)t * HDIM);
  float4 xv[4];
#pragma unroll
  for (int i = 0; i < 4; i++) xv[i] = xr[l + 64 * i];
  float part[NTOT];
#pragma unroll
  for (int e = 0; e < NTOT; e++) {
    const float4* wr = (const float4*)(rw + (size_t)e * HDIM);
    float s = 0.f;
#pragma unroll
    for (int i = 0; i < 4; i++) {
      float4 w = wr[l + 64 * i];
      s += xv[i].x * w.x + xv[i].y * w.y + xv[i].z * w.z + xv[i].w * w.w;
    }
    part[e] = s;
  }
#pragma unroll
  for (int off = 32; off > 0; off >>= 1)
#pragma unroll
    for (int e = 0; e < NTOT; e++) part[e] += __shfl_down(part[e], off);

  if (l == 0) {
    float mx = part[0];
#pragma unroll
    for (int e = 1; e < NTOT; e++) mx = fmaxf(mx, part[e]);
    float p[NTOT], den = 0.f;
#pragma unroll
    for (int e = 0; e < NTOT; e++) { p[e] = expf(part[e] - mx); den += p[e]; }
    float inv = 1.f / den;
#pragma unroll
    for (int e = 0; e < NTOT; e++) p[e] *= inv;
    float s0 = -1e30f, s1 = -1e30f; int i0 = 0, i1 = 0;
#pragma unroll
    for (int e = 0; e < NTOT; e++) {
      float v = p[e] + bias[e];
      if (v > s0) { s1 = s0; i1 = i0; s0 = v; i0 = e; }
      else if (v > s1) { s1 = v; i1 = e; }
    }
    float zs = 0.f;
    int idx[2] = { i0, i1 };
#pragma unroll
    for (int k = 0; k < 2; k++) {
      int e = idx[k];
      float w = p[e];
      if (e >= NEXP) { zs += w; tk_e[2 * t + k] = -1; tk_w[2 * t + k] = 0.f; }
      else           { tk_e[2 * t + k] = e; tk_w[2 * t + k] = w; }
    }
    zscale[t] = zs;
  }
}

// ---------------- zero init ----------------
__global__ void zero_init_kernel(int* __restrict__ counts, int* __restrict__ sel_tok,
                                 float* __restrict__ sel_w) {
  int i = blockIdx.x * blockDim.x + threadIdx.x;
  if (i < MAXROWS) { sel_tok[i] = 0; sel_w[i] = 0.f; }
  if (i < NEXP) counts[i] = 0;
}

// ---------------- count ----------------
__global__ void count_kernel(const int* __restrict__ tk_e, int* __restrict__ counts) {
  __shared__ int lc[NEXP];
  int tid = threadIdx.x;
  if (tid < NEXP) lc[tid] = 0;
  __syncthreads();
  int t = blockIdx.x * blockDim.x + tid;
  int e0 = tk_e[2 * t], e1 = tk_e[2 * t + 1];
  if (e0 >= 0) atomicAdd(&lc[e0], 1);
  if (e1 >= 0) atomicAdd(&lc[e1], 1);
  __syncthreads();
  if (tid < NEXP) atomicAdd(&counts[tid], lc[tid]);
}

// ---------------- scan: 128-padded offsets + compact tile list ----------------
__global__ void scan_kernel(const int* __restrict__ counts, int* __restrict__ off_pad,
                            int* __restrict__ cursor, int* __restrict__ total_rows,
                            int* __restrict__ tile_e, int* __restrict__ tile_p0,
                            int* __restrict__ n_mtiles) {
  if (threadIdx.x == 0) {
    int run = 0, nt = 0;
    for (int e = 0; e < NEXP; e++) {
      off_pad[e] = run;
      cursor[e] = run;
      int ntile = (counts[e] + 127) / 128;
      for (int i = 0; i < ntile; i++) {
        tile_e[nt] = e;
        tile_p0[nt] = run + i * 128;
        nt++;
      }
      run += ntile * 128;
    }
    *total_rows = run;
    *n_mtiles = nt;
  }
}

// ---------------- assign ----------------
__global__ void assign_kernel(const int* __restrict__ tk_e, const float* __restrict__ tk_w,
                              int* __restrict__ cursor, int* __restrict__ sel_tok,
                              float* __restrict__ sel_w, int* __restrict__ pos) {
  __shared__ int lc[NEXP];
  __shared__ int lbase[NEXP];
  int tid = threadIdx.x;
  if (tid < NEXP) lc[tid] = 0;
  __syncthreads();
  int t = blockIdx.x * blockDim.x + tid;
  int e0 = tk_e[2 * t], e1 = tk_e[2 * t + 1];
  int r0 = (e0 >= 0) ? atomicAdd(&lc[e0], 1) : -1;
  int r1 = (e1 >= 0) ? atomicAdd(&lc[e1], 1) : -1;
  __syncthreads();
  if (tid < NEXP) lbase[tid] = atomicAdd(&cursor[tid], lc[tid]);
  __syncthreads();
  int p0 = -1, p1 = -1;
  if (e0 >= 0) { p0 = lbase[e0] + r0; sel_tok[p0] = t; sel_w[p0] = 2.5f * tk_w[2 * t]; }
  if (e1 >= 0) { p1 = lbase[e1] + r1; sel_tok[p1] = t; sel_w[p1] = 2.5f * tk_w[2 * t + 1]; }
  pos[2 * t] = p0;
  pos[2 * t + 1] = p1;
}

// ---------------- gather+cast: xg[p,:] = bf16(x[sel_tok[p],:]) ----------------
__global__ void gather_cast_kernel(const float* __restrict__ x, const int* __restrict__ sel_tok,
                                   const int* __restrict__ total_rows, bf16_t* __restrict__ xg) {
  size_t gid = (size_t)blockIdx.x * blockDim.x + threadIdx.x;
  size_t p = gid >> 7;
  if (p >= (size_t)*total_rows) return;
  size_t j = (gid & 127) << 3;
  int t = sel_tok[p];
  float4 a = *(const float4*)&x[(size_t)t * HDIM + j];
  float4 b = *(const float4*)&x[(size_t)t * HDIM + j + 4];
  bf16x8 o;
  o[0] = (bf16_t)a.x; o[1] = (bf16_t)a.y; o[2] = (bf16_t)a.z; o[3] = (bf16_t)a.w;
  o[4] = (bf16_t)b.x; o[5] = (bf16_t)b.y; o[6] = (bf16_t)b.z; o[7] = (bf16_t)b.w;
  *(bf16x8*)&xg[p * HDIM + j] = o;
}

// ---------------- fused GEMM1+SiLU over compact tile list ----------------
// B-tile row r -> w13 col: g0 + (r>>6)*32 + (((r>>4)&1)*16) + (r&15), +512 if (r>>5)&1
// wave wc's acc[mt][nt] (nt<2)=gate, acc[mt][nt+2]=matching up, same lane.
__global__ __launch_bounds__(256) void gemm1_kernel(
    const bf16_t* __restrict__ xg, const bf16_t* __restrict__ w13b,
    const int* __restrict__ tile_e, const int* __restrict__ tile_p0,
    const int* __restrict__ n_mtiles, bf16_t* __restrict__ actb) {
  const int ti = blockIdx.x;
  if (ti >= *n_mtiles) return;
  const int e = tile_e[ti];
  const int p0 = tile_p0[ti];
  const int g0 = blockIdx.y * 64;

  __shared__ alignas(16) bf16_t As[128 * 32];
  __shared__ alignas(16) bf16_t Bs[128 * 32];
  const int tid = threadIdx.x;
  const int w = tid >> 6, l = tid & 63;
  const int wr = w >> 1, wc = w & 1;
  const int quad = l >> 4, c16 = l & 15;

  const int sr = w * 32 + (l >> 2);
  const int sc = (l & 3) * 8;
  const bf16_t* Ag0 = xg + (size_t)(p0 + sr) * HDIM + sc;
  const bf16_t* w13e = w13b + (size_t)e * (2 * IDIM) * HDIM;
  int r0 = sr, r1 = sr + 16;
  int col0 = g0 + (r0 >> 6) * 32 + (((r0 >> 4) & 1) * 16) + (r0 & 15) + (((r0 >> 5) & 1) ? IDIM : 0);
  int col1 = g0 + (r1 >> 6) * 32 + (((r1 >> 4) & 1) * 16) + (r1 & 15) + (((r1 >> 5) & 1) ? IDIM : 0);
  const bf16_t* Bg0 = w13e + (size_t)col0 * HDIM + sc;
  const bf16_t* Bg1 = w13e + (size_t)col1 * HDIM + sc;
  bf16_t* Al0 = &As[(w * 32) * 32];
  bf16_t* Bl0 = &Bs[(w * 32) * 32];

  f32x4 acc[4][4];
#pragma unroll
  for (int i = 0; i < 4; i++)
#pragma unroll
    for (int j = 0; j < 4; j++) acc[i][j] = (f32x4){0.f, 0.f, 0.f, 0.f};

  for (int k0 = 0; k0 < HDIM; k0 += 32) {
    gll16(Ag0 + k0, Al0);
    gll16(Ag0 + k0 + (size_t)16 * HDIM, Al0 + 16 * 32);
    gll16(Bg0 + k0, Bl0);
    gll16(Bg1 + k0, Bl0 + 16 * 32);
    __syncthreads();
    bf16x8 af[4], bfv[4];
#pragma unroll
    for (int mt = 0; mt < 4; mt++)
      af[mt] = *(const bf16x8*)&As[(wr * 64 + mt * 16 + c16) * 32 + quad * 8];
#pragma unroll
    for (int nt = 0; nt < 4; nt++)
      bfv[nt] = *(const bf16x8*)&Bs[(wc * 64 + nt * 16 + c16) * 32 + quad * 8];
#pragma unroll
    for (int mt = 0; mt < 4; mt++)
#pragma unroll
      for (int nt = 0; nt < 4; nt++)
        acc[mt][nt] = __builtin_amdgcn_mfma_f32_16x16x32_bf16(af[mt], bfv[nt], acc[mt][nt], 0, 0, 0);
    __syncthreads();
  }

#pragma unroll
  for (int mt = 0; mt < 4; mt++) {
    int rowb = p0 + wr * 64 + mt * 16 + quad * 4;
#pragma unroll
    for (int nt = 0; nt < 2; nt++) {
      int col = g0 + wc * 32 + nt * 16 + c16;
#pragma unroll
      for (int r = 0; r < 4; r++) {
        float g = acc[mt][nt][r];
        float u = acc[mt][nt + 2][r];
        float s = g / (1.f + expf(-g));
        actb[(size_t)(rowb + r) * IDIM + col] = (bf16_t)(s * u);
      }
    }
  }
}

// ---------------- GEMM2 over compact tile list ----------------
__global__ __launch_bounds__(256) void gemm2_kernel(
    const bf16_t* __restrict__ actb, const bf16_t* __restrict__ w2b,
    const float* __restrict__ sel_w, const int* __restrict__ tile_e,
    const int* __restrict__ tile_p0, const int* __restrict__ n_mtiles,
    bf16_t* __restrict__ eob) {
  const int ti = blockIdx.x;
  if (ti >= *n_mtiles) return;
  const int e = tile_e[ti];
  const int p0 = tile_p0[ti];
  const int n0 = blockIdx.y * 128;

  __shared__ alignas(16) bf16_t As[128 * 32];
  __shared__ alignas(16) bf16_t Bs[128 * 32];
  const int tid = threadIdx.x;
  const int w = tid >> 6, l = tid & 63;
  const int wr = w >> 1, wc = w & 1;
  const int quad = l >> 4, c16 = l & 15;

  const int sr = w * 32 + (l >> 2);
  const int sc = (l & 3) * 8;
  const bf16_t* Ag0 = actb + (size_t)(p0 + sr) * IDIM + sc;
  const bf16_t* Bg0 = w2b + (size_t)e * HDIM * IDIM + (size_t)(n0 + sr) * IDIM + sc;
  bf16_t* Al0 = &As[(w * 32) * 32];
  bf16_t* Bl0 = &Bs[(w * 32) * 32];

  f32x4 acc[4][4];
#pragma unroll
  for (int i = 0; i < 4; i++)
#pragma unroll
    for (int j = 0; j < 4; j++) acc[i][j] = (f32x4){0.f, 0.f, 0.f, 0.f};

  for (int k0 = 0; k0 < IDIM; k0 += 32) {
    gll16(Ag0 + k0, Al0);
    gll16(Ag0 + k0 + (size_t)16 * IDIM, Al0 + 16 * 32);
    gll16(Bg0 + k0, Bl0);
    gll16(Bg0 + k0 + (size_t)16 * IDIM, Bl0 + 16 * 32);
    __syncthreads();
    bf16x8 af[4], bfv[4];
#pragma unroll
    for (int mt = 0; mt < 4; mt++)
      af[mt] = *(const bf16x8*)&As[(wr * 64 + mt * 16 + c16) * 32 + quad * 8];
#pragma unroll
    for (int nt = 0; nt < 4; nt++)
      bfv[nt] = *(const bf16x8*)&Bs[(wc * 64 + nt * 16 + c16) * 32 + quad * 8];
#pragma unroll
    for (int mt = 0; mt < 4; mt++)
#pragma unroll
      for (int nt = 0; nt < 4; nt++)
        acc[mt][nt] = __builtin_amdgcn_mfma_f32_16x16x32_bf16(af[mt], bfv[nt], acc[mt][nt], 0, 0, 0);
    __syncthreads();
  }

#pragma unroll
  for (int mt = 0; mt < 4; mt++) {
    int rowb = wr * 64 + mt * 16 + quad * 4;
    float cw[4];
#pragma unroll
    for (int r = 0; r < 4; r++) cw[r] = sel_w[p0 + rowb + r];
#pragma unroll
    for (int nt = 0; nt < 4; nt++) {
      int col = n0 + wc * 64 + nt * 16 + c16;
#pragma unroll
      for (int r = 0; r < 4; r++)
        eob[(size_t)(p0 + rowb + r) * HDIM + col] = (bf16_t)(cw[r] * acc[mt][nt][r]);
    }
  }
}

// ---------------- final combine ----------------
__global__ void combine_kernel(const float* __restrict__ x, const float* __restrict__ zscale,
                               const int* __restrict__ pos, const bf16_t* __restrict__ eob,
                               float* __restrict__ out) {
  size_t gid = (size_t)blockIdx.x * blockDim.x + threadIdx.x;
  size_t t = gid >> 7;
  size_t j = (gid & 127) << 3;
  float zs = zscale[t];
  int p0 = pos[2 * t], p1 = pos[2 * t + 1];
  float4 a = *(const float4*)&x[t * HDIM + j];
  float4 b = *(const float4*)&x[t * HDIM + j + 4];
  float o[8] = { zs * a.x, zs * a.y, zs * a.z, zs * a.w,
                 zs * b.x, zs * b.y, zs * b.z, zs * b.w };
  if (p0 >= 0) {
    bf16x8 v = *(const bf16x8*)&eob[(size_t)p0 * HDIM + j];
#pragma unroll
    for (int k = 0; k < 8; k++) o[k] += (float)v[k];
  }
  if (p1 >= 0) {
    bf16x8 v = *(const bf16x8*)&eob[(size_t)p1 * HDIM + j];
#pragma unroll
    for (int k = 0; k < 8; k++) o[k] += (float)v[k];
  }
  *(float4*)&out[t * HDIM + j] = make_float4(o[0], o[1], o[2], o[3]);
  *(float4*)&out[t * HDIM + j + 4] = make_float4(o[4], o[5], o[6], o[7]);
}

extern "C" void kernel_launch(void* const* d_in, const int* in_sizes, int n_in,
                              void* d_out, int out_size, void* d_ws, size_t ws_size,
                              hipStream_t stream) {
  const float* x    = (const float*)d_in[0];
  const float* rw   = (const float*)d_in[1];
  const float* bias = (const float*)d_in[2];
  const float* w13  = (const float*)d_in[3];
  const float* w2   = (const float*)d_in[4];
  float* out = (float*)d_out;

  char* ws = (char*)d_ws;
  bf16_t* w13b = (bf16_t*)ws;  ws += (size_t)NEXP * 2 * IDIM * HDIM * 2;
  bf16_t* w2b  = (bf16_t*)ws;  ws += (size_t)NEXP * HDIM * IDIM * 2;
  bf16_t* xg   = (bf16_t*)ws;  ws += (size_t)MAXROWS * HDIM * 2;
  bf16_t* actb = (bf16_t*)ws;  ws += (size_t)MAXROWS * IDIM * 2;
  bf16_t* eob  = (bf16_t*)ws;  ws += (size_t)MAXROWS * HDIM * 2;
  int*   tk_e    = (int*)ws;   ws += (size_t)T_TOK * 2 * 4;
  float* tk_w    = (float*)ws; ws += (size_t)T_TOK * 2 * 4;
  float* zscale  = (float*)ws; ws += (size_t)T_TOK * 4;
  int*   pos     = (int*)ws;   ws += (size_t)T_TOK * 2 * 4;
  int*   sel_tok = (int*)ws;   ws += (size_t)MAXROWS * 4;
  float* sel_w   = (float*)ws; ws += (size_t)MAXROWS * 4;
  int*   counts  = (int*)ws;   ws += NEXP * 4;
  int*   off_pad = (int*)ws;   ws += NEXP * 4;
  int*   cursor  = (int*)ws;   ws += NEXP * 4;
  int*   total_rows = (int*)ws; ws += 4;
  int*   tile_e  = (int*)ws;   ws += MAX_MTILES * 4;
  int*   tile_p0 = (int*)ws;   ws += MAX_MTILES * 4;
  int*   n_mtiles = (int*)ws;  ws += 4;

  // weight casts
  {
    size_t n8 = (size_t)NEXP * 2 * IDIM * HDIM / 8;
    cast_bf16_kernel<<<(n8 + 255) / 256, 256, 0, stream>>>(w13, w13b, n8);
    n8 = (size_t)NEXP * HDIM * IDIM / 8;
    cast_bf16_kernel<<<(n8 + 255) / 256, 256, 0, stream>>>(w2, w2b, n8);
  }
  // routing pipeline
  router_kernel<<<T_TOK, 64, 0, stream>>>(x, rw, bias, tk_e, tk_w, zscale);
  zero_init_kernel<<<(MAXROWS + 255) / 256, 256, 0, stream>>>(counts, sel_tok, sel_w);
  count_kernel<<<T_TOK / 256, 256, 0, stream>>>(tk_e, counts);
  scan_kernel<<<1, 64, 0, stream>>>(counts, off_pad, cursor, total_rows,
                                    tile_e, tile_p0, n_mtiles);
  assign_kernel<<<T_TOK / 256, 256, 0, stream>>>(tk_e, tk_w, cursor, sel_tok, sel_w, pos);
  gather_cast_kernel<<<(size_t)MAXROWS * (HDIM / 8) / 256, 256, 0, stream>>>(
      x, sel_tok, total_rows, xg);

  // fused GEMM1 + SiLU-gate over compact tile list (all active blocks co-resident)
  gemm1_kernel<<<dim3(MAX_MTILES, IDIM / 64), 256, 0, stream>>>(
      xg, w13b, tile_e, tile_p0, n_mtiles, actb);
  // GEMM2 over compact tile list
  gemm2_kernel<<<dim3(MAX_MTILES, HDIM / 128), 256, 0, stream>>>(
      actb, w2b, sel_w, tile_e, tile_p0, n_mtiles, eob);

  // out = zscale*x + routed contributions
  combine_kernel<<<(size_t)T_TOK * HDIM / 8 / 256, 256, 0, stream>>>(
      x, zscale, pos, eob, out);
}